// Round 7
// baseline (216.719 us; speedup 1.0000x reference)
//
#include <hip/hip_runtime.h>
#include <hip/hip_fp16.h>
#include <math.h>

#define NITERS 50

typedef _Float16 h2_t __attribute__((ext_vector_type(2)));

#if defined(__has_builtin)
#if __has_builtin(__builtin_amdgcn_fdot2)
#define HAVE_FDOT2 1
#endif
#endif

__device__ __forceinline__ float fdot2f(unsigned int ka, unsigned int kb, float acc) {
#ifdef HAVE_FDOT2
    return __builtin_amdgcn_fdot2(__builtin_bit_cast(h2_t, ka),
                                  __builtin_bit_cast(h2_t, kb), acc, false);
#else
    h2_t a = __builtin_bit_cast(h2_t, ka);
    h2_t b = __builtin_bit_cast(h2_t, kb);
    return acc + (float)a.x * (float)b.x + (float)a.y * (float)b.y;
#endif
}

// One workgroup per batch. K0 built once in LDS (XOR-swizzled rows). Role-split
// waves: threads 0-255 each own a FULL ROW of K0 in registers (128 VGPR),
// threads 256-511 each own a FULL COLUMN (staged once, packed along i).
// Each Sinkhorn update is then thread-local (128 fdot2 + one powf + one fp16
// LDS store); 2 barriers/iteration, zero reduction traffic. u=v=0 throughout
// (rescale provably never fires early; absorption exact: K_fin = K0*a_i*b_j).
__global__ __launch_bounds__(512, 2) void wfr_kernel(const float* __restrict__ D,
                                                     float* __restrict__ out) {
    __shared__ __align__(16) __half Ksh[256 * 256];   // 128 KiB (build+stage only)
    __shared__ __align__(16) float  sh_bf[256];
    __shared__ __align__(16) __half sh_bh[256];
    __shared__ __align__(16) __half sh_ah[256];
    __shared__ __align__(16) float  part[8];

    const int tid = threadIdx.x;
    const int bb  = blockIdx.x;
    char* Kbytes  = reinterpret_cast<char*>(Ksh);

    // ---- build K0 = exp(-C/eps) = c^20,  c = cos(min(2D, pi/2)) + 1e-5 ----
    {
        const float4* D4 = reinterpret_cast<const float4*>(D + (size_t)bb * 65536);
        for (int k = 0; k < 32; ++k) {
            int idx4 = tid + (k << 9);            // 64 float4 per row -> wave == one row
            float4 d = D4[idx4];
            int i = idx4 >> 6;
            int j = (idx4 & 63) << 2;
            float v0[4] = {d.x, d.y, d.z, d.w};
            float k0[4];
            #pragma unroll
            for (int q = 0; q < 4; ++q) {
                float c = cosf(fminf(v0[q] * 2.0f, 1.57079632679489662f)) + 1e-5f;
                k0[q] = expf(20.0f * logf(c));    // == exp(-C/eps)
            }
            h2_t h01 = { (_Float16)k0[0], (_Float16)k0[1] };
            h2_t h23 = { (_Float16)k0[2], (_Float16)k0[3] };
            uint2 wv;
            wv.x = __builtin_bit_cast(unsigned int, h01);
            wv.y = __builtin_bit_cast(unsigned int, h23);
            int off = (i << 9) + (((j << 1) ^ ((i & 31) << 4)));
            *reinterpret_cast<uint2*>(Kbytes + off) = wv;
        }
    }
    if (tid < 256) {
        sh_bf[tid] = 1.0f;
        sh_bh[tid] = __float2half(1.0f);
    }
    __syncthreads();

    const bool is_row = (tid < 256);   // wave-uniform (waves 0-3 vs 4-7)
    const int  r  = tid & 255;         // row id (row-threads) / col id (col-threads)

    // ---- stage K slice into registers (once) ----
    uint4 kreg[32];                    // 128 VGPRs: full row OR full column (fp16 x256)
    if (is_row) {
        const char* Krow = Kbytes + (r << 9);
        const int rsw = r & 31;
        #pragma unroll
        for (int c = 0; c < 32; ++c)
            kreg[c] = *reinterpret_cast<const uint4*>(Krow + ((c ^ rsw) << 4));
    } else {
        #pragma unroll
        for (int c = 0; c < 32; ++c) {
            unsigned int w[4];
            #pragma unroll
            for (int h = 0; h < 4; ++h) {
                int i0 = (c << 3) + (h << 1);
                int i1 = i0 + 1;
                unsigned int lo = *reinterpret_cast<const unsigned short*>(
                    Kbytes + (i0 << 9) + ((r << 1) ^ ((i0 & 31) << 4)));
                unsigned int hi = *reinterpret_cast<const unsigned short*>(
                    Kbytes + (i1 << 9) + ((r << 1) ^ ((i1 & 31) << 4)));
                w[h] = lo | (hi << 16);
            }
            kreg[c].x = w[0]; kreg[c].y = w[1]; kreg[c].z = w[2]; kreg[c].w = w[3];
        }
    }

    float a_local = 0.0f, b_local = 0.0f, s2m_local = 0.0f;

    for (int it = 0; it < NITERS; ++it) {
        // ---------- row phase: s_i = mean_j K0[i][j]*b[j]; a_i local ----------
        if (is_row) {
            float s0 = 0.0f, s1 = 0.0f, sa = 0.0f, sb = 0.0f;
            #pragma unroll
            for (int c = 0; c < 32; ++c) {
                uint4 bv = *reinterpret_cast<const uint4*>(
                    reinterpret_cast<const char*>(sh_bh) + (c << 4));  // broadcast
                s0 = fdot2f(kreg[c].x, bv.x, s0);
                s1 = fdot2f(kreg[c].y, bv.y, s1);
                sa = fdot2f(kreg[c].z, bv.z, sa);
                sb = fdot2f(kreg[c].w, bv.w, sb);
            }
            float sf = ((s0 + s1) + (sa + sb)) * (1.0f / 256.0f);
            float a  = __powf(sf, -(1.0f / 1.1f));   // (1/s)^(1/(1+eps))
            a = fminf(a, 1e30f);
            a_local = a;
            sh_ah[r] = __float2half(a);
        }
        __syncthreads();
        // ---------- col phase: s2_j = mean_i K0[i][j]*a[i]; b_j local ----------
        if (!is_row) {
            float s0 = 0.0f, s1 = 0.0f, sa = 0.0f, sb = 0.0f;
            #pragma unroll
            for (int c = 0; c < 32; ++c) {
                uint4 av = *reinterpret_cast<const uint4*>(
                    reinterpret_cast<const char*>(sh_ah) + (c << 4));  // broadcast
                s0 = fdot2f(kreg[c].x, av.x, s0);
                s1 = fdot2f(kreg[c].y, av.y, s1);
                sa = fdot2f(kreg[c].z, av.z, sa);
                sb = fdot2f(kreg[c].w, av.w, sb);
            }
            s2m_local = ((s0 + s1) + (sa + sb)) * (1.0f / 256.0f);
            float bn = __powf(s2m_local, -(1.0f / 1.1f));
            bn = fminf(bn, 1e30f);
            b_local = bn;
            sh_bf[r] = bn;
            sh_bh[r] = __float2half(bn);
        }
        __syncthreads();
    }

    // ---- epilogue: K_fin = K0*a_i*b_j ; C = -0.1*ln(K0) ----
    float val;
    if (is_row) {
        float s = 0.0f, tp = 0.0f;
        #pragma unroll
        for (int c = 0; c < 32; ++c) {
            float4 blo = *reinterpret_cast<const float4*>(sh_bf + (c << 3));
            float4 bhi = *reinterpret_cast<const float4*>(sh_bf + (c << 3) + 4);
            h2_t p0 = __builtin_bit_cast(h2_t, kreg[c].x);
            h2_t p1 = __builtin_bit_cast(h2_t, kreg[c].y);
            h2_t p2 = __builtin_bit_cast(h2_t, kreg[c].z);
            h2_t p3 = __builtin_bit_cast(h2_t, kreg[c].w);
            float kf[8] = {(float)p0.x,(float)p0.y,(float)p1.x,(float)p1.y,
                           (float)p2.x,(float)p2.y,(float)p3.x,(float)p3.y};
            float bf[8] = {blo.x,blo.y,blo.z,blo.w,bhi.x,bhi.y,bhi.z,bhi.w};
            #pragma unroll
            for (int q = 0; q < 8; ++q) {
                float prod = kf[q] * bf[q];
                s += prod;
                float cl = (kf[q] > 0.0f) ? (-0.1f * __logf(kf[q])) : 0.0f;
                tp = fmaf(prod, cl, tp);
            }
        }
        float row_marg = a_local * s * (1.0f / 256.0f);
        float d1  = row_marg / (1.0f + 1e-10f);
        float kl1 = d1 * __logf(d1 + 1e-10f) - d1 + 1.0f;
        val = kl1 * (1.0f / 256.0f) + (a_local * tp) * (1.0f / 65536.0f);
    } else {
        float col_marg = b_local * s2m_local;    // b_j * mean_i K0*a
        float d2  = col_marg / (1.0f + 1e-10f);
        float kl2 = d2 * __logf(d2 + 1e-10f) - d2 + 1.0f;
        val = kl2 * (1.0f / 256.0f);
    }

    // ---- reduce 512 -> 1 (wave shuffle + tiny LDS tree) ----
    #pragma unroll
    for (int off = 32; off > 0; off >>= 1)
        val += __shfl_down(val, off, 64);
    if ((tid & 63) == 0) part[tid >> 6] = val;
    __syncthreads();
    if (tid == 0) {
        float t = 0.0f;
        #pragma unroll
        for (int w = 0; w < 8; ++w) t += part[w];
        out[bb] = t;
    }
}

extern "C" void kernel_launch(void* const* d_in, const int* in_sizes, int n_in,
                              void* d_out, int out_size, void* d_ws, size_t ws_size,
                              hipStream_t stream) {
    (void)in_sizes; (void)n_in; (void)d_ws; (void)ws_size; (void)out_size;
    const float* D = reinterpret_cast<const float*>(d_in[0]);
    float* out     = reinterpret_cast<float*>(d_out);
    wfr_kernel<<<dim3(256), dim3(512), 0, stream>>>(D, out);
}